// Round 5
// baseline (1388.041 us; speedup 1.0000x reference)
//
#include <hip/hip_runtime.h>
#include <hip/hip_bf16.h>

typedef __bf16 bf16x8 __attribute__((ext_vector_type(8)));
typedef float  f32x4  __attribute__((ext_vector_type(4)));

// ---------------------------------------------------------------------------
// async global->LDS, 16B per lane. Dest is wave-uniform base + lane*16.
__device__ __forceinline__ void gload16(const __bf16* g, __bf16* l) {
  __builtin_amdgcn_global_load_lds(
      (const __attribute__((address_space(1))) void*)g,
      (__attribute__((address_space(3))) void*)l, 16, 0, 0);
}

// Stage one K-half unit: 256 rows x 32 bf16 (16 KiB). LDS written linearly;
// SOURCE permuted so content is XOR-swizzled: logical 8-elem slot s of row r
// lives at phys slot s ^ ((r>>1)&3). 2 global_load_lds per wave (512 thr).
// g must point at tile base + khalf*32.
__device__ __forceinline__ void stage_u(const __bf16* __restrict__ g, int ld,
                                        __bf16* l, int wid, int lane) {
#pragma unroll
  for (int p = 0; p < 2; ++p) {
    int cbase = p * 512 + wid * 64;   // 16B chunk index of lane 0
    int c     = cbase + lane;
    int row   = c >> 2;               // 4 chunks (64B) per row
    int sl    = (c & 3) ^ ((row >> 1) & 3);
    gload16(g + (long)row * ld + sl * 8, l + cbase * 8);
  }
}

// swizzled byte offset within a unit for logical (row R, slot s)
__device__ __forceinline__ int foff(int R, int s) {
  return R * 64 + ((s ^ ((R >> 1) & 3)) << 4);
}

#define MFMA16(MH)                                                        \
  __builtin_amdgcn_s_setprio(1);                                          \
  _Pragma("unroll") for (int i = 0; i < 4; ++i)                           \
      _Pragma("unroll") for (int n = 0; n < 4; ++n)                       \
          acc[(MH)*4 + i][n] = __builtin_amdgcn_mfma_f32_16x16x32_bf16(   \
              af[i], bf[n], acc[(MH)*4 + i][n], 0, 0, 0);                 \
  __builtin_amdgcn_s_setprio(0);

#define PH_SYNC()                                                         \
  __builtin_amdgcn_sched_barrier(0);                                      \
  __builtin_amdgcn_s_barrier();                                           \
  asm volatile("s_waitcnt lgkmcnt(0)" ::: "memory");                      \
  __builtin_amdgcn_sched_barrier(0);

#define PH_END()                                                          \
  __builtin_amdgcn_sched_barrier(0);                                      \
  __builtin_amdgcn_s_barrier();

// One K-tile = 4 phases (Khalf h x Mhalf mh), 16 MFMA each.
// Stage ledger: ph0: A-h1(t+1), ph1: B-h1(t+1), ph2: A-h0(t+2), ph3: B-h0(t+2)
// + vmcnt(4). VAR: 0 steady; 1 = stage ph0/1 only, vmcnt(0); 2 = none.
template <int VAR>
__device__ __forceinline__ void ktile(
    const __bf16* gaT1, const __bf16* gbT1,  // tile t+1 base
    const __bf16* gaT2, const __bf16* gbT2,  // tile t+2 base
    int lda, int ldb,
    const __bf16* lA0, const __bf16* lA1,
    const __bf16* lB0, const __bf16* lB1,
    __bf16* wA1, __bf16* wB1, __bf16* wA0, __bf16* wB0,
    int wid, int wr, int wc, int lane, f32x4 (&acc)[8][4]) {
  const int rl = lane & 15, s = lane >> 4;
  bf16x8 af[4], bf[4];

  // ---- phase 0: h=0, mh=0 (reads af+bf, stages A-h1 of t+1)
#pragma unroll
  for (int i = 0; i < 4; ++i)
    af[i] = *(const bf16x8*)((const char*)lA0 + foff(wr * 128 + i * 16 + rl, s));
#pragma unroll
  for (int n = 0; n < 4; ++n)
    bf[n] = *(const bf16x8*)((const char*)lB0 + foff(wc * 64 + n * 16 + rl, s));
  if constexpr (VAR <= 1) stage_u(gaT1 + 32, lda, wA1, wid, lane);
  PH_SYNC();
  MFMA16(0);
  PH_END();

  // ---- phase 1: h=0, mh=1 (reuses bf, stages B-h1 of t+1)
#pragma unroll
  for (int i = 0; i < 4; ++i)
    af[i] = *(const bf16x8*)((const char*)lA0 +
                             foff(wr * 128 + 64 + i * 16 + rl, s));
  if constexpr (VAR <= 1) stage_u(gbT1 + 32, ldb, wB1, wid, lane);
  PH_SYNC();
  MFMA16(1);
  PH_END();

  // ---- phase 2: h=1, mh=0 (reads af+bf, stages A-h0 of t+2)
#pragma unroll
  for (int i = 0; i < 4; ++i)
    af[i] = *(const bf16x8*)((const char*)lA1 + foff(wr * 128 + i * 16 + rl, s));
#pragma unroll
  for (int n = 0; n < 4; ++n)
    bf[n] = *(const bf16x8*)((const char*)lB1 + foff(wc * 64 + n * 16 + rl, s));
  if constexpr (VAR == 0) stage_u(gaT2, lda, wA0, wid, lane);
  PH_SYNC();
  MFMA16(0);
  PH_END();

  // ---- phase 3: h=1, mh=1 (reuses bf, stages B-h0 of t+2, counted wait)
#pragma unroll
  for (int i = 0; i < 4; ++i)
    af[i] = *(const bf16x8*)((const char*)lA1 +
                             foff(wr * 128 + 64 + i * 16 + rl, s));
  if constexpr (VAR == 0) stage_u(gbT2, ldb, wB0, wid, lane);
  if constexpr (VAR == 0) asm volatile("s_waitcnt vmcnt(4)" ::: "memory");
  if constexpr (VAR == 1) asm volatile("s_waitcnt vmcnt(0)" ::: "memory");
  PH_SYNC();
  MFMA16(1);
  PH_END();
}

// ---------------------------------------------------------------------------
// C[M][N] = A[M][K] * Bt[N][K]^T  (row-major, K contiguous).
// 256x256 tile, BK=64, 512 thr = 8 waves (2M x 4N), wave out 128x64.
// Double-buffered K-half-unit LDS (128 KiB), 4 fine phases/K-tile,
// counted vmcnt(4), setprio, bijective XCD swizzle (nwg % 8 == 0).
// __launch_bounds__(512, 1): 256-VGPR budget — acc[8][4] alone is 128 VGPR;
// (512, 2) capped at 128 and spilled the accumulator to scratch (R4: 1 GB
// WRITE_SIZE, 620 us/dispatch). LDS=128 KiB limits to 1 block/CU anyway.
template <int OUTBF16, int BIASMODE, int DOSCALE>
__global__ __launch_bounds__(512, 1) void gemm4(
    const __bf16* __restrict__ A, const __bf16* __restrict__ Bt,
    const float* __restrict__ bias, const float* __restrict__ bias2,
    void* __restrict__ Cv, int lda, int ldb, int ldc, int K,
    long sA, long sB, long sC, float scale) {
  __shared__ __align__(16) __bf16 ldsA[2][2][256 * 32];  // [buf][khalf] 64 KiB
  __shared__ __align__(16) __bf16 ldsB[2][2][256 * 32];  // 64 KiB

  const int tid = threadIdx.x, wid = tid >> 6, lane = tid & 63;
  const int wr = wid >> 2, wc = wid & 3;

  // T1: bijective XCD swizzle of flat block id
  const int gx = gridDim.x, gy = gridDim.y;
  const int nwg = gx * gy * (int)gridDim.z;
  int flat = ((int)blockIdx.z * gy + (int)blockIdx.y) * gx + (int)blockIdx.x;
  flat = (flat & 7) * (nwg >> 3) + (flat >> 3);
  const int bx = flat % gx;
  const int by = (flat / gx) % gy;
  const int bz = flat / (gx * gy);

  const long brow = (long)by * 256;
  const long bcol = (long)bx * 256;
  const __bf16* ga = A + bz * sA + brow * lda;
  const __bf16* gb = Bt + bz * sB + bcol * ldb;
  const int nk = K >> 6;

  f32x4 acc[8][4];
#pragma unroll
  for (int m = 0; m < 8; ++m)
#pragma unroll
    for (int n = 0; n < 4; ++n) acc[m][n] = (f32x4){0.f, 0.f, 0.f, 0.f};

  // prologue: tile0 all 4 units, tile1 h0 units (12 loads/wave)
  stage_u(ga, lda, ldsA[0][0], wid, lane);
  stage_u(gb, ldb, ldsB[0][0], wid, lane);
  stage_u(ga + 32, lda, ldsA[0][1], wid, lane);
  stage_u(gb + 32, ldb, ldsB[0][1], wid, lane);
  stage_u(ga + 64, lda, ldsA[1][0], wid, lane);
  stage_u(gb + 64, ldb, ldsB[1][0], wid, lane);
  asm volatile("s_waitcnt vmcnt(4)" ::: "memory");  // tile0 landed
  __builtin_amdgcn_s_barrier();

  for (int t = 0; t < nk; ++t) {
    const int cur = t & 1;
    if (t < nk - 2)
      ktile<0>(ga + (t + 1) * 64, gb + (t + 1) * 64, ga + (t + 2) * 64,
               gb + (t + 2) * 64, lda, ldb, ldsA[cur][0], ldsA[cur][1],
               ldsB[cur][0], ldsB[cur][1], ldsA[cur ^ 1][1], ldsB[cur ^ 1][1],
               ldsA[cur][0], ldsB[cur][0], wid, wr, wc, lane, acc);
    else if (t == nk - 2)
      ktile<1>(ga + (t + 1) * 64, gb + (t + 1) * 64, ga, gb, lda, ldb,
               ldsA[cur][0], ldsA[cur][1], ldsB[cur][0], ldsB[cur][1],
               ldsA[cur ^ 1][1], ldsB[cur ^ 1][1], ldsA[cur][0], ldsB[cur][0],
               wid, wr, wc, lane, acc);
    else
      ktile<2>(ga, gb, ga, gb, lda, ldb, ldsA[cur][0], ldsA[cur][1],
               ldsB[cur][0], ldsB[cur][1], ldsA[cur ^ 1][1], ldsB[cur ^ 1][1],
               ldsA[cur][0], ldsB[cur][0], wid, wr, wc, lane, acc);
  }

  // epilogue: C/D layout col = lane&15, row = (lane>>4)*4 + reg
  const long cb = (long)bz * sC;
#pragma unroll
  for (int m = 0; m < 8; ++m) {
    const int row = (int)brow + wr * 128 + (m >> 2) * 64 + (m & 3) * 16 +
                    ((lane >> 4) << 2);
#pragma unroll
    for (int n = 0; n < 4; ++n) {
      const int col = (int)bcol + wc * 64 + n * 16 + (lane & 15);
#pragma unroll
      for (int r = 0; r < 4; ++r) {
        float v = acc[m][n][r];
        if (DOSCALE) v *= scale;
        if (BIASMODE == 1) v += (col < 1024) ? bias[col] : bias2[col - 1024];
        if (BIASMODE == 2) v += bias[row + r];
        if (OUTBF16)
          ((__bf16*)Cv)[cb + (long)(row + r) * ldc + col] = (__bf16)v;
        else
          ((float*)Cv)[cb + (long)(row + r) * ldc + col] = v;
      }
    }
  }
}

// ---------------------------------------------------------------------------
// x fp32 -> bf16, 8 elements/thread, exact coverage
__global__ __launch_bounds__(256) void convert_x(const float* __restrict__ x,
                                                 __bf16* __restrict__ o) {
  const long i = ((long)blockIdx.x * 256 + threadIdx.x) * 8;
  float4 a = *(const float4*)(x + i);
  float4 b = *(const float4*)(x + i + 4);
  bf16x8 v;
  v[0] = (__bf16)a.x; v[1] = (__bf16)a.y; v[2] = (__bf16)a.z; v[3] = (__bf16)a.w;
  v[4] = (__bf16)b.x; v[5] = (__bf16)b.y; v[6] = (__bf16)b.z; v[7] = (__bf16)b.w;
  *(bf16x8*)(o + i) = v;
}

// W[1024][1024] fp32 -> Wt[1024][1024] bf16 transposed; 64x64 tiles.
__global__ __launch_bounds__(256) void transpose_w(
    const float* __restrict__ W0, const float* __restrict__ W1,
    const float* __restrict__ W2, __bf16* __restrict__ T0,
    __bf16* __restrict__ T1, __bf16* __restrict__ T2) {
  const float* W = blockIdx.z == 0 ? W0 : (blockIdx.z == 1 ? W1 : W2);
  __bf16* T      = blockIdx.z == 0 ? T0 : (blockIdx.z == 1 ? T1 : T2);
  __shared__ float t[64][65];
  const int e0 = blockIdx.x * 64, d0 = blockIdx.y * 64;
  const int tr = threadIdx.x >> 2, tc = (threadIdx.x & 3) * 16;
  const float* src = W + (long)(d0 + tr) * 1024 + e0 + tc;
#pragma unroll
  for (int i = 0; i < 4; ++i) {
    float4 v = *(const float4*)(src + i * 4);
    t[tr][tc + i * 4 + 0] = v.x;
    t[tr][tc + i * 4 + 1] = v.y;
    t[tr][tc + i * 4 + 2] = v.z;
    t[tr][tc + i * 4 + 3] = v.w;
  }
  __syncthreads();
  __bf16* dst = T + (long)(e0 + tr) * 1024 + d0 + tc;
  bf16x8 v0, v1;
#pragma unroll
  for (int i = 0; i < 8; ++i) v0[i] = (__bf16)t[tc + i][tr];
#pragma unroll
  for (int i = 0; i < 8; ++i) v1[i] = (__bf16)t[tc + 8 + i][tr];
  *(bf16x8*)dst = v0;
  *(bf16x8*)(dst + 8) = v1;
}

// in-place row softmax over 2048 bf16, one block per row, fp32 reduction
__global__ __launch_bounds__(256) void softmax_rows(__bf16* __restrict__ P) {
  __bf16* p = P + (long)blockIdx.x * 2048;
  const int t = threadIdx.x, wid = t >> 6, lane = t & 63;
  bf16x8 v = *(bf16x8*)(p + t * 8);
  float f[8];
  float mx = -1e30f;
#pragma unroll
  for (int i = 0; i < 8; ++i) { f[i] = (float)v[i]; mx = fmaxf(mx, f[i]); }
#pragma unroll
  for (int o = 32; o > 0; o >>= 1) mx = fmaxf(mx, __shfl_xor(mx, o));
  __shared__ float redm[4], reds[4];
  if (lane == 0) redm[wid] = mx;
  __syncthreads();
  mx = fmaxf(fmaxf(redm[0], redm[1]), fmaxf(redm[2], redm[3]));
  float s = 0.f;
#pragma unroll
  for (int i = 0; i < 8; ++i) { f[i] = __expf(f[i] - mx); s += f[i]; }
#pragma unroll
  for (int o = 32; o > 0; o >>= 1) s += __shfl_xor(s, o);
  if (lane == 0) reds[wid] = s;
  __syncthreads();
  s = reds[0] + reds[1] + reds[2] + reds[3];
  const float inv = 1.0f / s;
#pragma unroll
  for (int i = 0; i < 8; ++i) v[i] = (__bf16)(f[i] * inv);
  *(bf16x8*)(p + t * 8) = v;
}

// ---------------------------------------------------------------------------
extern "C" void kernel_launch(void* const* d_in, const int* in_sizes, int n_in,
                              void* d_out, int out_size, void* d_ws,
                              size_t ws_size, hipStream_t stream) {
  const float* x  = (const float*)d_in[0];
  const float* Wq = (const float*)d_in[1];
  const float* bq = (const float*)d_in[2];
  const float* Wk = (const float*)d_in[3];
  const float* bk = (const float*)d_in[4];
  const float* Wv = (const float*)d_in[5];
  const float* bv = (const float*)d_in[6];
  float* out = (float*)d_out;

  char* ws = (char*)d_ws;
  __bf16* xb   = (__bf16*)(ws);                 // 16 MB: x bf16 [8192][1024]
  __bf16* wqkt = (__bf16*)(ws + (16l << 20));   //  4 MB: [Wq^T; Wk^T]
  __bf16* wvt  = (__bf16*)(ws + (20l << 20));   //  2 MB: Wv^T [1024][1024]
  __bf16* qk   = (__bf16*)(ws + (22l << 20));   // 32 MB: [Q|K] [8192][2048]
  __bf16* vt   = (__bf16*)(ws + (54l << 20));   // 16 MB: V^T [1024][8192]
  __bf16* S    = (__bf16*)(ws + (70l << 20));   // 32 MB: S/P [4][2048][2048]

  convert_x<<<4096, 256, 0, stream>>>(x, xb);
  transpose_w<<<dim3(16, 16, 3), 256, 0, stream>>>(
      Wq, Wk, Wv, wqkt, wqkt + 1024l * 1024, wvt);

  // [Q|K] = xb * [Wq^T;Wk^T]^T + [bq|bk]  (M=8192, N=2048, K=1024)
  gemm4<1, 1, 0><<<dim3(8, 32, 1), 512, 0, stream>>>(
      xb, wqkt, bq, bk, qk, 1024, 1024, 2048, 1024, 0, 0, 0, 1.f);
  // V^T: Vt[e][token] (M=1024 feats, N=8192 tokens), bias per ROW
  gemm4<1, 2, 0><<<dim3(32, 4, 1), 512, 0, stream>>>(
      wvt, xb, bv, nullptr, vt, 1024, 1024, 8192, 1024, 0, 0, 0, 1.f);

  // S = Q K^T * (1/32)  per batch (M=N=2048, K=1024), bf16 out
  gemm4<1, 0, 1><<<dim3(8, 8, 4), 512, 0, stream>>>(
      qk, qk + 1024, nullptr, nullptr, S, 2048, 2048, 2048, 1024,
      2048l * 2048, 2048l * 2048, 2048l * 2048, 0.03125f);

  softmax_rows<<<8192, 256, 0, stream>>>(S);

  // O = P V  per batch (M=2048, N=1024, K=2048), fp32 out to d_out
  gemm4<0, 0, 0><<<dim3(4, 8, 4), 512, 0, stream>>>(
      S, vt, nullptr, nullptr, out, 2048, 8192, 1024, 2048,
      2048l * 2048, 2048, 2048l * 1024, 1.f);
}

// Round 6
// 191.341 us; speedup vs baseline: 7.2543x; 7.2543x over previous
//
#include <hip/hip_runtime.h>
#include <hip/hip_bf16.h>

typedef __bf16 bf16x8 __attribute__((ext_vector_type(8)));
typedef float  f32x4  __attribute__((ext_vector_type(4)));

// ---------------------------------------------------------------------------
// async global->LDS, 16B per lane. Dest is wave-uniform base + lane*16.
__device__ __forceinline__ void gload16(const __bf16* g, __bf16* l) {
  __builtin_amdgcn_global_load_lds(
      (const __attribute__((address_space(1))) void*)g,
      (__attribute__((address_space(3))) void*)l, 16, 0, 0);
}

// Stage one K-half unit: 256 rows x 32 bf16 (16 KiB). LDS written linearly;
// SOURCE permuted so content is XOR-swizzled: logical 8-elem slot s of row r
// lives at phys slot s ^ ((r>>1)&3). 2 global_load_lds per wave (512 thr).
__device__ __forceinline__ void stage_u(const __bf16* __restrict__ g, int ld,
                                        __bf16* l, int wid, int lane) {
#pragma unroll
  for (int p = 0; p < 2; ++p) {
    int cbase = p * 512 + wid * 64;   // 16B chunk index of lane 0
    int c     = cbase + lane;
    int row   = c >> 2;               // 4 chunks (64B) per row
    int sl    = (c & 3) ^ ((row >> 1) & 3);
    gload16(g + (long)row * ld + sl * 8, l + cbase * 8);
  }
}

// swizzled byte offset within a unit for logical (row R, slot s)
__device__ __forceinline__ int foff(int R, int s) {
  return R * 64 + ((s ^ ((R >> 1) & 3)) << 4);
}

#define BAR() asm volatile("s_barrier" ::: "memory")

#define MFMA16(MH)                                                        \
  __builtin_amdgcn_s_setprio(1);                                          \
  _Pragma("unroll") for (int i = 0; i < 4; ++i)                           \
      _Pragma("unroll") for (int n = 0; n < 4; ++n)                       \
          acc[(MH)*4 + i][n] = __builtin_amdgcn_mfma_f32_16x16x32_bf16(   \
              af[i], bf[n], acc[(MH)*4 + i][n], 0, 0, 0);                 \
  __builtin_amdgcn_s_setprio(0);

// ---------------------------------------------------------------------------
// C[M][N] = A[M][K] * Bt[N][K]^T  (row-major, K contiguous).
// 256x256 tile, BK=64, 512 thr = 8 waves (2M x 4N), wave out 128x64.
// Double-buffered K-half-unit LDS (128 KiB), 4 fine phases/K-tile, counted
// vmcnt(4) once per K-tile, setprio, bijective XCD swizzle (nwg % 8 == 0).
// NOTE: no sched_barrier(0) walls and no manual lgkmcnt — C++ ds_reads give
// the compiler SSA deps (it emits its own lgkmcnt before dependent MFMAs);
// asm s_barrier w/ memory clobber pins cross-phase memory order. The R4/R5
// sched_barrier walls inflated live ranges past the 8-wave VGPR cap and
// spilled acc to scratch (1 GB WRITE_SIZE, 620 us/dispatch).
// Stage ledger per tile t (buffers: parity cur = t&1):
//   ph0: read A-h0 rows[0,64)+B-h0, stage A-h1(t+1) -> [cur^1][1]
//   ph1: read A-h0 rows[64,128) (reuse bf), stage B-h1(t+1)
//   ph2: read A-h1+B-h1,              stage A-h0(t+2) -> [cur][0]
//   ph3: read A-h1 rows[64,128) (reuse bf), stage B-h0(t+2), vmcnt(4)
// vmcnt(4) leaves exactly the 4 h0(t+2) loads in flight; everything older
// (incl. both h-units of tile t+1) has landed before the closing barrier.
template <int OUTBF16, int BIASMODE, int DOSCALE>
__global__ __launch_bounds__(512) void gemm5(
    const __bf16* __restrict__ A, const __bf16* __restrict__ Bt,
    const float* __restrict__ bias, const float* __restrict__ bias2,
    void* __restrict__ Cv, int lda, int ldb, int ldc, int K,
    long sA, long sB, long sC, float scale) {
  __shared__ __align__(16) __bf16 ldsA[2][2][256 * 32];  // [buf][khalf] 64 KiB
  __shared__ __align__(16) __bf16 ldsB[2][2][256 * 32];  // 64 KiB

  const int tid = threadIdx.x, wid = tid >> 6, lane = tid & 63;
  const int wr = wid >> 2, wc = wid & 3;
  const int rl = lane & 15, s = lane >> 4;

  // T1: bijective XCD swizzle of flat block id
  const int gx = gridDim.x, gy = gridDim.y;
  const int nwg = gx * gy * (int)gridDim.z;
  int flat = ((int)blockIdx.z * gy + (int)blockIdx.y) * gx + (int)blockIdx.x;
  flat = (flat & 7) * (nwg >> 3) + (flat >> 3);
  const int bx = flat % gx;
  const int by = (flat / gx) % gy;
  const int bz = flat / (gx * gy);

  const long brow = (long)by * 256;
  const long bcol = (long)bx * 256;
  const __bf16* ga = A + bz * sA + brow * lda;
  const __bf16* gb = Bt + bz * sB + bcol * ldb;
  const int nk = K >> 6;

  f32x4 acc[8][4];
#pragma unroll
  for (int m = 0; m < 8; ++m)
#pragma unroll
    for (int n = 0; n < 4; ++n) acc[m][n] = (f32x4){0.f, 0.f, 0.f, 0.f};

  // prologue: tile0 all 4 units + tile1 h0 units; full drain (one-time) so
  // steady-state vmcnt counts are independent of prologue issue order.
  stage_u(ga, lda, ldsA[0][0], wid, lane);
  stage_u(gb, ldb, ldsB[0][0], wid, lane);
  stage_u(ga + 32, lda, ldsA[0][1], wid, lane);
  stage_u(gb + 32, ldb, ldsB[0][1], wid, lane);
  stage_u(ga + 64, lda, ldsA[1][0], wid, lane);
  stage_u(gb + 64, ldb, ldsB[1][0], wid, lane);
  asm volatile("s_waitcnt vmcnt(0)" ::: "memory");
  BAR();

  for (int t = 0; t < nk; ++t) {
    const int cur = t & 1;
    const char* A0 = (const char*)ldsA[cur][0];
    const char* A1 = (const char*)ldsA[cur][1];
    const char* B0 = (const char*)ldsB[cur][0];
    const char* B1 = (const char*)ldsB[cur][1];
    bf16x8 af[4], bf[4];

    // ---- phase 0: K-half 0, M-half 0; stage A-h1(t+1)
#pragma unroll
    for (int i = 0; i < 4; ++i)
      af[i] = *(const bf16x8*)(A0 + foff(wr * 128 + i * 16 + rl, s));
#pragma unroll
    for (int n = 0; n < 4; ++n)
      bf[n] = *(const bf16x8*)(B0 + foff(wc * 64 + n * 16 + rl, s));
    if (t + 1 < nk)
      stage_u(ga + (t + 1) * 64 + 32, lda, ldsA[cur ^ 1][1], wid, lane);
    MFMA16(0);
    BAR();

    // ---- phase 1: K-half 0, M-half 1 (reuse bf); stage B-h1(t+1)
#pragma unroll
    for (int i = 0; i < 4; ++i)
      af[i] = *(const bf16x8*)(A0 + foff(wr * 128 + 64 + i * 16 + rl, s));
    if (t + 1 < nk)
      stage_u(gb + (t + 1) * 64 + 32, ldb, ldsB[cur ^ 1][1], wid, lane);
    MFMA16(1);
    BAR();

    // ---- phase 2: K-half 1, M-half 0; stage A-h0(t+2)
#pragma unroll
    for (int i = 0; i < 4; ++i)
      af[i] = *(const bf16x8*)(A1 + foff(wr * 128 + i * 16 + rl, s));
#pragma unroll
    for (int n = 0; n < 4; ++n)
      bf[n] = *(const bf16x8*)(B1 + foff(wc * 64 + n * 16 + rl, s));
    if (t + 2 < nk)
      stage_u(ga + (t + 2) * 64, lda, ldsA[cur][0], wid, lane);
    MFMA16(0);
    BAR();

    // ---- phase 3: K-half 1, M-half 1 (reuse bf); stage B-h0(t+2) + wait
#pragma unroll
    for (int i = 0; i < 4; ++i)
      af[i] = *(const bf16x8*)(A1 + foff(wr * 128 + 64 + i * 16 + rl, s));
    if (t + 2 < nk) {
      stage_u(gb + (t + 2) * 64, ldb, ldsB[cur][0], wid, lane);
      asm volatile("s_waitcnt vmcnt(4)" ::: "memory");
    } else if (t + 1 < nk) {
      asm volatile("s_waitcnt vmcnt(0)" ::: "memory");
    }
    MFMA16(1);
    BAR();
  }

  // epilogue: C/D layout col = lane&15, row = (lane>>4)*4 + reg
  const long cb = (long)bz * sC;
#pragma unroll
  for (int m = 0; m < 8; ++m) {
    const int row = (int)brow + wr * 128 + (m >> 2) * 64 + (m & 3) * 16 +
                    ((lane >> 4) << 2);
#pragma unroll
    for (int n = 0; n < 4; ++n) {
      const int col = (int)bcol + wc * 64 + n * 16 + (lane & 15);
#pragma unroll
      for (int r = 0; r < 4; ++r) {
        float v = acc[m][n][r];
        if (DOSCALE) v *= scale;
        if (BIASMODE == 1) v += (col < 1024) ? bias[col] : bias2[col - 1024];
        if (BIASMODE == 2) v += bias[row + r];
        if (OUTBF16)
          ((__bf16*)Cv)[cb + (long)(row + r) * ldc + col] = (__bf16)v;
        else
          ((float*)Cv)[cb + (long)(row + r) * ldc + col] = v;
      }
    }
  }
}

// ---------------------------------------------------------------------------
// x fp32 -> bf16, 8 elements/thread, exact coverage
__global__ __launch_bounds__(256) void convert_x(const float* __restrict__ x,
                                                 __bf16* __restrict__ o) {
  const long i = ((long)blockIdx.x * 256 + threadIdx.x) * 8;
  float4 a = *(const float4*)(x + i);
  float4 b = *(const float4*)(x + i + 4);
  bf16x8 v;
  v[0] = (__bf16)a.x; v[1] = (__bf16)a.y; v[2] = (__bf16)a.z; v[3] = (__bf16)a.w;
  v[4] = (__bf16)b.x; v[5] = (__bf16)b.y; v[6] = (__bf16)b.z; v[7] = (__bf16)b.w;
  *(bf16x8*)(o + i) = v;
}

// W[1024][1024] fp32 -> Wt[1024][1024] bf16 transposed; 64x64 tiles.
__global__ __launch_bounds__(256) void transpose_w(
    const float* __restrict__ W0, const float* __restrict__ W1,
    const float* __restrict__ W2, __bf16* __restrict__ T0,
    __bf16* __restrict__ T1, __bf16* __restrict__ T2) {
  const float* W = blockIdx.z == 0 ? W0 : (blockIdx.z == 1 ? W1 : W2);
  __bf16* T      = blockIdx.z == 0 ? T0 : (blockIdx.z == 1 ? T1 : T2);
  __shared__ float t[64][65];
  const int e0 = blockIdx.x * 64, d0 = blockIdx.y * 64;
  const int tr = threadIdx.x >> 2, tc = (threadIdx.x & 3) * 16;
  const float* src = W + (long)(d0 + tr) * 1024 + e0 + tc;
#pragma unroll
  for (int i = 0; i < 4; ++i) {
    float4 v = *(const float4*)(src + i * 4);
    t[tr][tc + i * 4 + 0] = v.x;
    t[tr][tc + i * 4 + 1] = v.y;
    t[tr][tc + i * 4 + 2] = v.z;
    t[tr][tc + i * 4 + 3] = v.w;
  }
  __syncthreads();
  __bf16* dst = T + (long)(e0 + tr) * 1024 + d0 + tc;
  bf16x8 v0, v1;
#pragma unroll
  for (int i = 0; i < 8; ++i) v0[i] = (__bf16)t[tc + i][tr];
#pragma unroll
  for (int i = 0; i < 8; ++i) v1[i] = (__bf16)t[tc + 8 + i][tr];
  *(bf16x8*)dst = v0;
  *(bf16x8*)(dst + 8) = v1;
}

// in-place row softmax over 2048 bf16, one block per row, fp32 reduction
__global__ __launch_bounds__(256) void softmax_rows(__bf16* __restrict__ P) {
  __bf16* p = P + (long)blockIdx.x * 2048;
  const int t = threadIdx.x, wid = t >> 6, lane = t & 63;
  bf16x8 v = *(bf16x8*)(p + t * 8);
  float f[8];
  float mx = -1e30f;
#pragma unroll
  for (int i = 0; i < 8; ++i) { f[i] = (float)v[i]; mx = fmaxf(mx, f[i]); }
#pragma unroll
  for (int o = 32; o > 0; o >>= 1) mx = fmaxf(mx, __shfl_xor(mx, o));
  __shared__ float redm[4], reds[4];
  if (lane == 0) redm[wid] = mx;
  __syncthreads();
  mx = fmaxf(fmaxf(redm[0], redm[1]), fmaxf(redm[2], redm[3]));
  float s = 0.f;
#pragma unroll
  for (int i = 0; i < 8; ++i) { f[i] = __expf(f[i] - mx); s += f[i]; }
#pragma unroll
  for (int o = 32; o > 0; o >>= 1) s += __shfl_xor(s, o);
  if (lane == 0) reds[wid] = s;
  __syncthreads();
  s = reds[0] + reds[1] + reds[2] + reds[3];
  const float inv = 1.0f / s;
#pragma unroll
  for (int i = 0; i < 8; ++i) v[i] = (__bf16)(f[i] * inv);
  *(bf16x8*)(p + t * 8) = v;
}

// ---------------------------------------------------------------------------
extern "C" void kernel_launch(void* const* d_in, const int* in_sizes, int n_in,
                              void* d_out, int out_size, void* d_ws,
                              size_t ws_size, hipStream_t stream) {
  const float* x  = (const float*)d_in[0];
  const float* Wq = (const float*)d_in[1];
  const float* bq = (const float*)d_in[2];
  const float* Wk = (const float*)d_in[3];
  const float* bk = (const float*)d_in[4];
  const float* Wv = (const float*)d_in[5];
  const float* bv = (const float*)d_in[6];
  float* out = (float*)d_out;

  char* ws = (char*)d_ws;
  __bf16* xb   = (__bf16*)(ws);                 // 16 MB: x bf16 [8192][1024]
  __bf16* wqkt = (__bf16*)(ws + (16l << 20));   //  4 MB: [Wq^T; Wk^T]
  __bf16* wvt  = (__bf16*)(ws + (20l << 20));   //  2 MB: Wv^T [1024][1024]
  __bf16* qk   = (__bf16*)(ws + (22l << 20));   // 32 MB: [Q|K] [8192][2048]
  __bf16* vt   = (__bf16*)(ws + (54l << 20));   // 16 MB: V^T [1024][8192]
  __bf16* S    = (__bf16*)(ws + (70l << 20));   // 32 MB: S/P [4][2048][2048]

  convert_x<<<4096, 256, 0, stream>>>(x, xb);
  transpose_w<<<dim3(16, 16, 3), 256, 0, stream>>>(
      Wq, Wk, Wv, wqkt, wqkt + 1024l * 1024, wvt);

  // [Q|K] = xb * [Wq^T;Wk^T]^T + [bq|bk]  (M=8192, N=2048, K=1024)
  gemm5<1, 1, 0><<<dim3(8, 32, 1), 512, 0, stream>>>(
      xb, wqkt, bq, bk, qk, 1024, 1024, 2048, 1024, 0, 0, 0, 1.f);
  // V^T: Vt[e][token] (M=1024 feats, N=8192 tokens), bias per ROW
  gemm5<1, 2, 0><<<dim3(32, 4, 1), 512, 0, stream>>>(
      wvt, xb, bv, nullptr, vt, 1024, 1024, 8192, 1024, 0, 0, 0, 1.f);

  // S = Q K^T * (1/32)  per batch (M=N=2048, K=1024), bf16 out
  gemm5<1, 0, 1><<<dim3(8, 8, 4), 512, 0, stream>>>(
      qk, qk + 1024, nullptr, nullptr, S, 2048, 2048, 2048, 1024,
      2048l * 2048, 2048l * 2048, 2048l * 2048, 0.03125f);

  softmax_rows<<<8192, 256, 0, stream>>>(S);

  // O = P V  per batch (M=2048, N=1024, K=2048), fp32 out to d_out
  gemm5<0, 0, 0><<<dim3(4, 8, 4), 512, 0, stream>>>(
      S, vt, nullptr, nullptr, out, 2048, 8192, 1024, 2048,
      2048l * 2048, 2048, 2048l * 1024, 1.f);
}